// Round 4
// baseline (735.228 us; speedup 1.0000x reference)
//
#include <hip/hip_runtime.h>
#include <math.h>

// AlignmentLayer: B=4, C=2048, H=W=64 (P=4096), HID=256
// R4: projX-v2 -- transpose via packed f16 reg-staging (4x4 f32 block/lane,
//     b64 pair-writes into padded [64p][72c] LDS, b128 fragment reads) replaces
//     the 64x conflicted ds_read_b32 column reads. X(t+1) prefetch issued before
//     compute (T14); counted vmcnt keeps prefetch+V-stores in flight.
//     MFMA operand values/order unchanged -> bit-identical pipeline.
// Pipeline: prep_w, projXk (z=8), scr8 (8-phase), softmax8, out8 (8-phase).

#define BATCH 4
#define CH    2048
#define PP    4096
#define DD    256

typedef __bf16    bf16x8 __attribute__((ext_vector_type(8)));
typedef _Float16  f16x8  __attribute__((ext_vector_type(8)));
typedef _Float16  f16x4  __attribute__((ext_vector_type(4)));
typedef float     f32x4  __attribute__((ext_vector_type(4)));

__device__ __forceinline__ unsigned short f2bf(float f) {
  unsigned int u = __float_as_uint(f);
  unsigned int r = u + 0x7fffu + ((u >> 16) & 1u);   // RNE
  return (unsigned short)(r >> 16);
}

__device__ __forceinline__ unsigned int h16(float f) {
  _Float16 h = (_Float16)f;                          // RNE, same as v1 path
  unsigned short u;
  __builtin_memcpy(&u, &h, 2);
  return (unsigned int)u;
}

#define GLL(src, dst) \
  __builtin_amdgcn_global_load_lds( \
      (const __attribute__((address_space(1))) unsigned int*)(uintptr_t)(src), \
      (__attribute__((address_space(3))) unsigned int*)(uintptr_t)(dst), 16, 0, 0)

// ---------------- prep_w: W fp32 [o][c] -> fp16 ----------------
__global__ __launch_bounds__(256) void prep_w(
    const float* __restrict__ W, _Float16* __restrict__ Wf) {
  int i = blockIdx.x * 256 + threadIdx.x;          // float4 units, 131072
  float4 v = ((const float4*)W)[i];
  f16x4 h = {(_Float16)v.x, (_Float16)v.y, (_Float16)v.z, (_Float16)v.w};
  ((f16x4*)Wf)[i] = h;
}

// ---------------- projXk: Q/K projection fused with transpose (v2) ----------------
// grid (PP/64, 1, NZ), block 256 (4 waves). z' = zbase + blockIdx.z:
//   tensor = (z'&1) ? prompt : query, batch = z'>>1.
// Per k-iter (c0 += 64):
//   1. GLL W[256o][64c] -> Ws swizzled 128B rows (8 instr/wave)
//   2. issue X(t+1) loads (4x dwordx4/lane: rows 4vL..+3, cols 4iL..+3)
//   3. cvt X(t)->f16, 4x b64 pair-writes -> LsT [64p][72c] (stride 144B)
//   4. V-emit bf16 from X(t) f32 regs (prompt only)
//   5. s_waitcnt vmcnt(8|4) lgkmcnt(0); barrier   [W landed; Xld+Vst in flight]
//   6. compute: per s-half, 4+4 ds_read_b128 frags + 16 MFMA (order == v1)
//   7. barrier; xv <- xn
__global__ __launch_bounds__(256) void projXk(
    const float* __restrict__ Xq, const float* __restrict__ Xp,
    const _Float16* __restrict__ Wf, const float* __restrict__ bias,
    unsigned short* __restrict__ Qh, unsigned short* __restrict__ Ql,
    unsigned short* __restrict__ Kh, unsigned short* __restrict__ Kl,
    unsigned short* __restrict__ Vb8, int zbase, int single) {
  const int z = zbase + blockIdx.z;
  const int b = z >> 1;
  const int ob = single ? 0 : b;
  const float* __restrict__ X =
      ((z & 1) ? Xp : Xq) + (size_t)b * CH * PP;
  unsigned short* __restrict__ Yh =
      ((z & 1) ? Kh : Qh) + (size_t)ob * PP * DD;
  unsigned short* __restrict__ Yl =
      ((z & 1) ? Kl : Ql) + (size_t)ob * PP * DD;
  unsigned short* __restrict__ Vb = Vb8 + (size_t)ob * CH * PP;
  const int emitV = (z & 1);

  const int pBase = blockIdx.x * 64;
  const int tid  = threadIdx.x;
  const int wave = tid >> 6;
  const int lane = tid & 63;
  const int row16 = lane & 15, quad = lane >> 4;
  const int iL = tid & 15;          // p-quad selector (p = 4iL + r)
  const int vL = tid >> 4;          // channel-quad selector (c = 4vL + cc)

  __shared__ __align__(16) char LdsP[32768 + 9216];
  char* Ws = LdsP;                                   // [256 o][128 B] swizzled
  unsigned int* LsT = (unsigned int*)(LdsP + 32768); // [64 p][36 words] f16

  // W staging (proven v1 pattern)
  const int wRowIn  = lane >> 3;
  const int wChunk  = (((lane & 7) ^ (lane >> 3)) << 4);

  f32x4 acc[4][4];
#pragma unroll
  for (int i = 0; i < 4; ++i)
#pragma unroll
    for (int j = 0; j < 4; ++j) acc[i][j] = (f32x4){0.f, 0.f, 0.f, 0.f};

  const float* Xl = X + (size_t)(4 * vL) * PP + pBase + 4 * iL;

  float4 xv[4], xn[4];
#pragma unroll
  for (int cc = 0; cc < 4; ++cc)
    xv[cc] = *(const float4*)(Xl + (size_t)cc * PP);
  __builtin_amdgcn_sched_barrier(0);

#pragma unroll 1
  for (int c0 = 0; c0 < CH - 64; c0 += 64) {
    // 1. GLL W slab
#pragma unroll
    for (int q = 0; q < 8; ++q) {
      const int g = wave * 8 + q;
      GLL((const char*)Wf + (size_t)(g * 8 + wRowIn) * (CH * 2) + c0 * 2 + wChunk,
          Ws + g * 1024);
    }
    __builtin_amdgcn_sched_barrier(0);
    // 2. prefetch X(t+1)
#pragma unroll
    for (int cc = 0; cc < 4; ++cc)
      xn[cc] = *(const float4*)(Xl + (size_t)(c0 + 64 + cc) * PP);
    __builtin_amdgcn_sched_barrier(0);
    // 3. transpose-write X(t) as f16 channel-pairs (b64)
#pragma unroll
    for (int r = 0; r < 4; ++r) {
      const float a0 = ((const float*)&xv[0])[r];
      const float a1 = ((const float*)&xv[1])[r];
      const float a2 = ((const float*)&xv[2])[r];
      const float a3 = ((const float*)&xv[3])[r];
      unsigned long long w = (unsigned long long)(h16(a0) | (h16(a1) << 16)) |
                             ((unsigned long long)(h16(a2) | (h16(a3) << 16)) << 32);
      *(unsigned long long*)&LsT[(4 * iL + r) * 36 + 2 * vL] = w;
    }
    // 4. V-emit from f32 regs (prompt only)
    if (emitV) {
#pragma unroll
      for (int cc = 0; cc < 4; ++cc) {
        float4 v = xv[cc];
        ushort4 o = {f2bf(v.x), f2bf(v.y), f2bf(v.z), f2bf(v.w)};
        *(ushort4*)&Vb[(size_t)(c0 + 4 * vL + cc) * PP + pBase + 4 * iL] = o;
      }
    }
    __builtin_amdgcn_sched_barrier(0);
    // 5. W landed; keep Xld(4) [+Vst(4)] in flight
    if (emitV) {
      asm volatile("s_waitcnt vmcnt(8) lgkmcnt(0)" ::: "memory");
    } else {
      asm volatile("s_waitcnt vmcnt(4) lgkmcnt(0)" ::: "memory");
    }
    __builtin_amdgcn_s_barrier();
    __builtin_amdgcn_sched_barrier(0);
    // 6. compute (identical operand values/order to v1)
#pragma unroll
    for (int s = 0; s < 2; ++s) {
      f16x8 af[4], bf[4];
#pragma unroll
      for (int i = 0; i < 4; ++i)
        af[i] = *(const f16x8*)((const char*)LsT +
                                (i * 16 + row16) * 144 + s * 64 + quad * 16);
#pragma unroll
      for (int j = 0; j < 4; ++j) {
        const int brow = wave * 64 + j * 16 + row16;
        bf[j] = *(const f16x8*)(Ws + brow * 128 +
                                (((s * 4 + quad) ^ (row16 & 7)) << 4));
      }
#pragma unroll
      for (int i = 0; i < 4; ++i)
#pragma unroll
        for (int j = 0; j < 4; ++j)
          acc[i][j] = __builtin_amdgcn_mfma_f32_16x16x32_f16(
              af[i], bf[j], acc[i][j], 0, 0, 0);
    }
    __builtin_amdgcn_sched_barrier(0);
    __builtin_amdgcn_s_barrier();
    // 7. advance regs
#pragma unroll
    for (int cc = 0; cc < 4; ++cc) xv[cc] = xn[cc];
  }

  // ---- peeled final k-iter (c0 = CH-64): no prefetch ----
  {
    const int c0 = CH - 64;
#pragma unroll
    for (int q = 0; q < 8; ++q) {
      const int g = wave * 8 + q;
      GLL((const char*)Wf + (size_t)(g * 8 + wRowIn) * (CH * 2) + c0 * 2 + wChunk,
          Ws + g * 1024);
    }
    __builtin_amdgcn_sched_barrier(0);
#pragma unroll
    for (int r = 0; r < 4; ++r) {
      const float a0 = ((const float*)&xv[0])[r];
      const float a1 = ((const float*)&xv[1])[r];
      const float a2 = ((const float*)&xv[2])[r];
      const float a3 = ((const float*)&xv[3])[r];
      unsigned long long w = (unsigned long long)(h16(a0) | (h16(a1) << 16)) |
                             ((unsigned long long)(h16(a2) | (h16(a3) << 16)) << 32);
      *(unsigned long long*)&LsT[(4 * iL + r) * 36 + 2 * vL] = w;
    }
    if (emitV) {
#pragma unroll
      for (int cc = 0; cc < 4; ++cc) {
        float4 v = xv[cc];
        ushort4 o = {f2bf(v.x), f2bf(v.y), f2bf(v.z), f2bf(v.w)};
        *(ushort4*)&Vb[(size_t)(c0 + 4 * vL + cc) * PP + pBase + 4 * iL] = o;
      }
    }
    __builtin_amdgcn_sched_barrier(0);
    if (emitV) {
      asm volatile("s_waitcnt vmcnt(4) lgkmcnt(0)" ::: "memory");
    } else {
      asm volatile("s_waitcnt vmcnt(0) lgkmcnt(0)" ::: "memory");
    }
    __builtin_amdgcn_s_barrier();
    __builtin_amdgcn_sched_barrier(0);
#pragma unroll
    for (int s = 0; s < 2; ++s) {
      f16x8 af[4], bf[4];
#pragma unroll
      for (int i = 0; i < 4; ++i)
        af[i] = *(const f16x8*)((const char*)LsT +
                                (i * 16 + row16) * 144 + s * 64 + quad * 16);
#pragma unroll
      for (int j = 0; j < 4; ++j) {
        const int brow = wave * 64 + j * 16 + row16;
        bf[j] = *(const f16x8*)(Ws + brow * 128 +
                                (((s * 4 + quad) ^ (row16 & 7)) << 4));
      }
#pragma unroll
      for (int i = 0; i < 4; ++i)
#pragma unroll
        for (int j = 0; j < 4; ++j)
          acc[i][j] = __builtin_amdgcn_mfma_f32_16x16x32_f16(
              af[i], bf[j], acc[i][j], 0, 0, 0);
    }
  }

  // ---- epilogue: bias + bf16 hi/lo split (identical to v1) ----
#pragma unroll
  for (int i = 0; i < 4; ++i)
#pragma unroll
    for (int j = 0; j < 4; ++j) {
      const int ocol = wave * 64 + j * 16 + row16;
      const float bv = bias[ocol];
#pragma unroll
      for (int r = 0; r < 4; ++r) {
        const int prow = pBase + i * 16 + quad * 4 + r;
        float y = acc[i][j][r] + bv;
        unsigned short h = f2bf(y);
        float hf = __uint_as_float((unsigned int)h << 16);
        unsigned short l = f2bf(y - hf);
        Yh[(size_t)prow * DD + ocol] = h;
        Yl[(size_t)prow * DD + ocol] = l;
      }
    }
}

// ---------------- softmax rows; writes bf16 in place, batched ----------------
// grid (PP, NB)
__global__ __launch_bounds__(256) void softmax8(float* __restrict__ S_) {
  float* __restrict__ Sb = S_ + (size_t)blockIdx.y * PP * PP;
  unsigned short* __restrict__ Ab = (unsigned short*)Sb;
  const size_t p = blockIdx.x;
  float* row = Sb + p * PP;
  const int tid = threadIdx.x;
  float4 v[4];
#pragma unroll
  for (int i = 0; i < 4; ++i)
    v[i] = *(const float4*)&row[(i * 256 + tid) * 4];
  float m = -1e30f;
#pragma unroll
  for (int i = 0; i < 4; ++i)
    m = fmaxf(m, fmaxf(fmaxf(v[i].x, v[i].y), fmaxf(v[i].z, v[i].w)));
#pragma unroll
  for (int off = 32; off > 0; off >>= 1)
    m = fmaxf(m, __shfl_xor(m, off));
  __shared__ float red[4];
  const int lane = tid & 63, wv = tid >> 6;
  if (lane == 0) red[wv] = m;
  __syncthreads();
  m = fmaxf(fmaxf(red[0], red[1]), fmaxf(red[2], red[3]));
  __syncthreads();
  float s = 0.f;
#pragma unroll
  for (int i = 0; i < 4; ++i) {
    v[i].x = __expf(v[i].x - m);
    v[i].y = __expf(v[i].y - m);
    v[i].z = __expf(v[i].z - m);
    v[i].w = __expf(v[i].w - m);
    s += v[i].x + v[i].y + v[i].z + v[i].w;
  }
#pragma unroll
  for (int off = 32; off > 0; off >>= 1)
    s += __shfl_xor(s, off);
  if (lane == 0) red[wv] = s;
  __syncthreads();
  s = red[0] + red[1] + red[2] + red[3];
  const float inv = 1.f / s;
  unsigned short* orow = Ab + p * 8192;
#pragma unroll
  for (int i = 0; i < 4; ++i) {
    ushort4 o;
    o.x = f2bf(v[i].x * inv); o.y = f2bf(v[i].y * inv);
    o.z = f2bf(v[i].z * inv); o.w = f2bf(v[i].w * inv);
    *(ushort4*)&orow[(i * 256 + tid) * 4] = o;
  }
}

// ======================= shared 8-phase template machinery =======================
// LDS 128KB: A regions d*32768+h*16384, B at +65536. Rows are 128B (8 chunks of
// 16B); swizzle chunk ^= (row&7), applied on pre-swizzled global source AND read.

#define AOFF(d, h) ((d) * 32768 + (h) * 16384)
#define BOFF(d, h) (65536 + (d) * 32768 + (h) * 16384)

#define PH_READ_A(d, mh) do {                                                  \
  _Pragma("unroll")                                                            \
  for (int m_ = 0; m_ < 4; ++m_) {                                             \
    const int ro_ = AOFF(d, wm) + ((mh) * 64 + m_ * 16 + row16) * 128;         \
    aR[m_][0] = *(const bf16x8*)(Lds + ro_ + cx0);                             \
    aR[m_][1] = *(const bf16x8*)(Lds + ro_ + cx1);                             \
  } } while (0)

#define PH_READ_B(d, nh, breg) do {                                            \
  _Pragma("unroll")                                                            \
  for (int n_ = 0; n_ < 2; ++n_) {                                             \
    const int ro_ = BOFF(d, wnh) + (wnl * 64 + (nh) * 32 + n_ * 16 + row16) * 128; \
    breg[n_][0] = *(const bf16x8*)(Lds + ro_ + cx0);                           \
    breg[n_][1] = *(const bf16x8*)(Lds + ro_ + cx1);                           \
  } } while (0)

// out8 flavor: cx0/cx1 are two successive k-halves of BK=64
#define PH_MFMA(mh, nh, breg) do {                                             \
  __builtin_amdgcn_s_setprio(1);                                               \
  _Pragma("unroll")                                                            \
  for (int m_ = 0; m_ < 4; ++m_)                                               \
  _Pragma("unroll")                                                            \
  for (int n_ = 0; n_ < 2; ++n_) {                                             \
    f32x4 a_ = acc[(mh) * 4 + m_][(nh) * 2 + n_];                              \
    a_ = __builtin_amdgcn_mfma_f32_16x16x32_bf16(aR[m_][0], breg[n_][0], a_, 0, 0, 0); \
    a_ = __builtin_amdgcn_mfma_f32_16x16x32_bf16(aR[m_][1], breg[n_][1], a_, 0, 0, 0); \
    acc[(mh) * 4 + m_][(nh) * 2 + n_] = a_;                                    \
  }                                                                            \
  __builtin_amdgcn_s_setprio(0); } while (0)

// scr8 flavor: cx0 = hi tensor, cx1 = lo tensor, same k; 3-term (hh, hl, lh)
#define PH_MFMA3(mh, nh, breg) do {                                            \
  __builtin_amdgcn_s_setprio(1);                                               \
  _Pragma("unroll")                                                            \
  for (int m_ = 0; m_ < 4; ++m_)                                               \
  _Pragma("unroll")                                                            \
  for (int n_ = 0; n_ < 2; ++n_) {                                             \
    f32x4 a_ = acc[(mh) * 4 + m_][(nh) * 2 + n_];                              \
    a_ = __builtin_amdgcn_mfma_f32_16x16x32_bf16(aR[m_][0], breg[n_][0], a_, 0, 0, 0); \
    a_ = __builtin_amdgcn_mfma_f32_16x16x32_bf16(aR[m_][0], breg[n_][1], a_, 0, 0, 0); \
    a_ = __builtin_amdgcn_mfma_f32_16x16x32_bf16(aR[m_][1], breg[n_][0], a_, 0, 0, 0); \
    acc[(mh) * 4 + m_][(nh) * 2 + n_] = a_;                                    \
  }                                                                            \
  __builtin_amdgcn_s_setprio(0); } while (0)

#define BAR_MID() do {                                                         \
  __builtin_amdgcn_sched_barrier(0);                                           \
  __builtin_amdgcn_s_barrier();                                                \
  asm volatile("s_waitcnt lgkmcnt(0)" ::: "memory");                           \
  __builtin_amdgcn_sched_barrier(0); } while (0)

#define BAR_END() __builtin_amdgcn_s_barrier()

// ---------------- out8: Out = V A^T -- 256x256 tile, 8-phase pipeline ----------------
// V: [CH][PP] bf16 (M side). A: [PP][8192] bf16 rows aliased over fp32 S (N side).
// Out: [CH][PP] fp32. K = PP = 4096, 64 tiles of BK=64.
__global__ __launch_bounds__(512, 2) void out8(
    const unsigned short* __restrict__ V_,
    const unsigned short* __restrict__ A_,
    float* __restrict__ O_) {
  const size_t z = blockIdx.z;
  const unsigned short* __restrict__ Vb = V_ + z * (size_t)CH * PP;
  const unsigned short* __restrict__ Ab = A_ + z * (size_t)PP * 8192;
  float* __restrict__ Ob = O_ + z * (size_t)CH * PP;

  const int pBase = blockIdx.x * 256;   // N (p columns)
  const int cBase = blockIdx.y * 256;   // M (channels)
  const int tid = threadIdx.x;
  const int wave = tid >> 6, lane = tid & 63;
  const int wm = wave >> 2;             // 0..1 (M)
  const int wn = wave & 3;              // 0..3 (N)
  const int wnh = wn >> 1, wnl = wn & 1;
  const int row16 = lane & 15, quad = lane >> 4;

  __shared__ __align__(16) char Lds[131072];

  const int swz = (row16 & 7) << 4;
  const int cx0 = ((quad) << 4) ^ swz;
  const int cx1 = ((4 + quad) << 4) ^ swz;

  const int stRow0 = (wave * 2 + 0) * 8 + (lane >> 3);
  const int stRow1 = (wave * 2 + 1) * 8 + (lane >> 3);
  const int stCol  = (((lane & 7) ^ (lane >> 3)) << 4);
  char* ldsSt0 = Lds + (wave * 2 + 0) * 1024;
  char* ldsSt1 = Lds + (wave * 2 + 1) * 1024;

  const size_t VLDG = (size_t)PP * 2;      // 8192 B
  const size_t ALDG = (size_t)8192 * 2;    // 16384 B

  auto STG = [&](int ldsOff, const void* gbase, size_t ldgB, int rowBase, int gkB) {
    const char* g0 = (const char*)gbase + (size_t)(rowBase + stRow0) * ldgB + gkB + stCol;
    const char* g1 = (const char*)gbase + (size_t)(rowBase + stRow1) * ldgB + gkB + stCol;
    GLL(g0, ldsSt0 + ldsOff);
    GLL(g1, ldsSt1 + ldsOff);
  };

  f32x4 acc[8][4];
#pragma unroll
  for (int i = 0; i < 8; ++i)
#pragma unroll
    for (int j = 0; j < 4; ++j) acc[i][j] = (f32x4){0.f, 0.f, 0.f, 0.f};

  bf16x8 aR[4][2], bLo[2][2], bHi[2][2];

  // ---- prologue: tile0 (B then A) into dbuf0, tile1 B-halves into dbuf1 ----
  STG(BOFF(0, 0), Ab, ALDG, pBase + 0,   0);
  STG(BOFF(0, 1), Ab, ALDG, pBase + 128, 0);
  STG(AOFF(0, 0), Vb, VLDG, cBase + 0,   0);
  STG(AOFF(0, 1), Vb, VLDG, cBase + 128, 0);
  STG(BOFF(1, 0), Ab, ALDG, pBase + 0,   128);
  STG(BOFF(1, 1), Ab, ALDG, pBase + 128, 128);
  asm volatile("s_waitcnt vmcnt(4)" ::: "memory");
  __builtin_amdgcn_s_barrier();

#pragma unroll 1
  for (int i = 0; i < 31; ++i) {
    const int t = 2 * i;
    const int gk1 = (t + 1) * 128, gk2 = (t + 2) * 128, gk3 = (t + 3) * 128;
    PH_READ_A(0, 0); PH_READ_B(0, 0, bLo);
    STG(AOFF(1, 0), Vb, VLDG, cBase + 0, gk1);
    BAR_MID(); PH_MFMA(0, 0, bLo); BAR_END();
    PH_READ_B(0, 1, bHi);
    STG(AOFF(1, 1), Vb, VLDG, cBase + 128, gk1);
    BAR_MID(); PH_MFMA(0, 1, bHi); BAR_END();
    PH_READ_A(0, 1);
    STG(BOFF(0, 0), Ab, ALDG, pBase + 0, gk2);
    BAR_MID(); PH_MFMA(1, 0, bLo); BAR_END();
    STG(BOFF(0, 1), Ab, ALDG, pBase + 128, gk2);
    BAR_MID(); PH_MFMA(1, 1, bHi);
    asm volatile("s_waitcnt vmcnt(4)" ::: "memory");
    BAR_END();
    PH_READ_A(1, 0); PH_READ_B(1, 0, bLo);
    STG(AOFF(0, 0), Vb, VLDG, cBase + 0, gk2);
    BAR_MID(); PH_MFMA(0, 0, bLo); BAR_END();
    PH_READ_B(1, 1, bHi);
    STG(AOFF(0, 1), Vb, VLDG, cBase + 128, gk2);
    BAR_MID(); PH_MFMA(0, 1, bHi); BAR_END();
    PH_READ_A(1, 1);
    STG(BOFF(1, 0), Ab, ALDG, pBase + 0, gk3);
    BAR_MID(); PH_MFMA(1, 0, bLo); BAR_END();
    STG(BOFF(1, 1), Ab, ALDG, pBase + 128, gk3);
    BAR_MID(); PH_MFMA(1, 1, bHi);
    asm volatile("s_waitcnt vmcnt(4)" ::: "memory");
    BAR_END();
  }

  // ---- peeled final iter (tiles 62, 63) ----
  {
    const int gk1 = 63 * 128;
    PH_READ_A(0, 0); PH_READ_B(0, 0, bLo);
    STG(AOFF(1, 0), Vb, VLDG, cBase + 0, gk1);
    BAR_MID(); PH_MFMA(0, 0, bLo); BAR_END();
    PH_READ_B(0, 1, bHi);
    STG(AOFF(1, 1), Vb, VLDG, cBase + 128, gk1);
    BAR_MID(); PH_MFMA(0, 1, bHi); BAR_END();
    PH_READ_A(0, 1);
    BAR_MID(); PH_MFMA(1, 0, bLo); BAR_END();
    BAR_MID(); PH_MFMA(1, 1, bHi);
    asm volatile("s_waitcnt vmcnt(0)" ::: "memory");
    BAR_END();
    PH_READ_A(1, 0); PH_READ_B(1, 0, bLo);
    BAR_MID(); PH_MFMA(0, 0, bLo); BAR_END();
    PH_READ_B(1, 1, bHi);
    BAR_MID(); PH_MFMA(0, 1, bHi); BAR_END();
    PH_READ_A(1, 1);
    BAR_MID(); PH_MFMA(1, 0, bLo); BAR_END();
    BAR_MID(); PH_MFMA(1, 1, bHi);
  }

#pragma unroll
  for (int mi = 0; mi < 8; ++mi)
#pragma unroll
    for (int nj = 0; nj < 4; ++nj) {
      const int col = pBase + wn * 64 + nj * 16 + row16;
      float* orow = Ob + (size_t)(cBase + wm * 128 + mi * 16 + quad * 4) * PP + col;
#pragma unroll
      for (int r = 0; r < 4; ++r)
        orow[(size_t)r * PP] = acc[mi][nj][r];
    }
}

// ---------------- scr8: S = (Qh+Ql)(Kh+Kl)^T -- 256x256 tile, 8-phase ----------------
// Same template as out8. LDS row = 128B packing [hi (chunks 0-3) | lo (chunks 4-7)]
// of one k-tile (BK=32 cols x 2B = 64B per tensor). K=256 -> 8 k-tiles, 3 iters+peel.
__global__ __launch_bounds__(512, 2) void scr8(
    const unsigned short* __restrict__ Qh_, const unsigned short* __restrict__ Ql_,
    const unsigned short* __restrict__ Kh_, const unsigned short* __restrict__ Kl_,
    float* __restrict__ S_) {
  const size_t z = blockIdx.z;
  const unsigned short* __restrict__ Qh = Qh_ + z * (size_t)PP * DD;
  const unsigned short* __restrict__ Ql = Ql_ + z * (size_t)PP * DD;
  const unsigned short* __restrict__ Kh = Kh_ + z * (size_t)PP * DD;
  const unsigned short* __restrict__ Kl = Kl_ + z * (size_t)PP * DD;
  float* __restrict__ S = S_ + z * (size_t)PP * PP;

  const int kBase = blockIdx.x * 256;   // N (key columns)
  const int pBase = blockIdx.y * 256;   // M (query rows)
  const int tid = threadIdx.x;
  const int wave = tid >> 6, lane = tid & 63;
  const int wm = wave >> 2;             // 0..1 (M)
  const int wn = wave & 3;              // 0..3 (N)
  const int wnh = wn >> 1, wnl = wn & 1;
  const int row16 = lane & 15, quad = lane >> 4;

  __shared__ __align__(16) char Lds[131072];

  const int swz = (row16 & 7) << 4;
  const int cx0 = ((quad) << 4) ^ swz;
  const int cx1 = ((4 + quad) << 4) ^ swz;

  const int stRow0 = (wave * 2 + 0) * 8 + (lane >> 3);
  const int stRow1 = (wave * 2 + 1) * 8 + (lane >> 3);
  const int cc   = (lane & 7) ^ (lane >> 3);
  const int ccB  = (cc & 3) * 16;            // byte within the tensor's k-slice
  const char* tQ = (const char*)((cc >> 2) ? Ql : Qh);
  const char* tK = (const char*)((cc >> 2) ? Kl : Kh);
  char* ldsSt0 = Lds + (wave * 2 + 0) * 1024;
  char* ldsSt1 = Lds + (wave * 2 + 1) * 1024;

  auto STG = [&](int ldsOff, const char* tbase, int rowBase, int tkB) {
    const char* g0 = tbase + (size_t)(rowBase + stRow0) * 512 + tkB + ccB;
    const char* g1 = tbase + (size_t)(rowBase + stRow1) * 512 + tkB + ccB;
    GLL(g0, ldsSt0 + ldsOff);
    GLL(g1, ldsSt1 + ldsOff);
  };

  f32x4 acc[8][4];
#pragma unroll
  for (int i = 0; i < 8; ++i)
#pragma unroll
    for (int j = 0; j < 4; ++j) acc[i][j] = (f32x4){0.f, 0.f, 0.f, 0.f};

  bf16x8 aR[4][2], bLo[2][2], bHi[2][2];

  // ---- prologue: tile0 B+A into dbuf0, tile1 B-halves into dbuf1 ----
  STG(BOFF(0, 0), tK, kBase + 0,   0);
  STG(BOFF(0, 1), tK, kBase + 128, 0);
  STG(AOFF(0, 0), tQ, pBase + 0,   0);
  STG(AOFF(0, 1), tQ, pBase + 128, 0);
  STG(BOFF(1, 0), tK, kBase + 0,   64);
  STG(BOFF(1, 1), tK, kBase + 128, 64);
  asm volatile("s_waitcnt vmcnt(4)" ::: "memory");
  __builtin_amdgcn_s_barrier();

#pragma unroll 1
  for (int i = 0; i < 3; ++i) {
    const int t = 2 * i;
    const int gk1 = (t + 1) * 64, gk2 = (t + 2) * 64, gk3 = (t + 3) * 64;
    PH_READ_A(0, 0); PH_READ_B(0, 0, bLo);
    STG(AOFF(1, 0), tQ, pBase + 0, gk1);
    BAR_MID(); PH_MFMA3(0, 0, bLo); BAR_END();
    PH_READ_B(0, 1, bHi);
    STG(AOFF(1, 1), tQ, pBase + 128, gk1);
    BAR_MID(); PH_MFMA3(0, 1, bHi); BAR_END();
    PH_READ_A(0, 1);
    STG(BOFF(0, 0), tK, kBase + 0, gk2);
    BAR_MID(); PH_MFMA3(1, 0, bLo); BAR_END();
    STG(BOFF(0, 1), tK, kBase + 128, gk2);
    BAR_MID(); PH_MFMA3(1, 1, bHi);
    asm volatile("s_waitcnt vmcnt(4)" ::: "memory");
    BAR_END();
    PH_READ_A(1, 0); PH_READ_B(1, 0, bLo);
    STG(AOFF(0, 0), tQ, pBase + 0, gk2);
    BAR_MID(); PH_MFMA3(0, 0, bLo); BAR_END();
    PH_READ_B(1, 1, bHi);
    STG(AOFF(0, 1), tQ, pBase + 128, gk2);
    BAR_MID(); PH_MFMA3(0, 1, bHi); BAR_END();
    PH_READ_A(1, 1);
    STG(BOFF(1, 0), tK, kBase + 0, gk3);
    BAR_MID(); PH_MFMA3(1, 0, bLo); BAR_END();
    STG(BOFF(1, 1), tK, kBase + 128, gk3);
    BAR_MID(); PH_MFMA3(1, 1, bHi);
    asm volatile("s_waitcnt vmcnt(4)" ::: "memory");
    BAR_END();
  }

  // ---- peeled final iter (k-tiles 6, 7) ----
  {
    const int gk1 = 7 * 64;
    PH_READ_A(0, 0); PH_READ_B(0, 0, bLo);
    STG(AOFF(1, 0), tQ, pBase + 0, gk1);
    BAR_MID(); PH_MFMA3(0, 0, bLo); BAR_END();
    PH_READ_B(0, 1, bHi);
    STG(AOFF(1, 1), tQ, pBase + 128, gk1);
    BAR_MID(); PH_MFMA3(0, 1, bHi); BAR_END();
    PH_READ_A(0, 1);
    BAR_MID(); PH_MFMA3(1, 0, bLo); BAR_END();
    BAR_MID(); PH_MFMA3(1, 1, bHi);
    asm volatile("s_waitcnt vmcnt(0)" ::: "memory");
    BAR_END();
    PH_READ_A(1, 0); PH_READ_B(1, 0, bLo);
    BAR_MID(); PH_MFMA3(0, 0, bLo); BAR_END();
    PH_READ_B(1, 1, bHi);
    BAR_MID(); PH_MFMA3(0, 1, bHi); BAR_END();
    PH_READ_A(1, 1);
    BAR_MID(); PH_MFMA3(1, 0, bLo); BAR_END();
    BAR_MID(); PH_MFMA3(1, 1, bHi);
  }

  // ---- epilogue: store S fp32 ----
#pragma unroll
  for (int mi = 0; mi < 8; ++mi)
#pragma unroll
    for (int nj = 0; nj < 4; ++nj) {
      const int kcol = kBase + wn * 64 + nj * 16 + row16;
      float* orow = S + (size_t)(pBase + wm * 128 + mi * 16 + quad * 4) * PP + kcol;
#pragma unroll
      for (int r = 0; r < 4; ++r)
        orow[(size_t)r * PP] = acc[mi][nj][r];
    }
}

extern "C" void kernel_launch(void* const* d_in, const int* in_sizes, int n_in,
                              void* d_out, int out_size, void* d_ws, size_t ws_size,
                              hipStream_t stream) {
  const float* Xq   = (const float*)d_in[0];
  const float* Xp   = (const float*)d_in[1];
  const float* Wg   = (const float*)d_in[2];
  const float* bias = (const float*)d_in[3];
  float* out = (float*)d_out;

  char* w = (char*)d_ws;
  const size_t MB = 1024 * 1024;
  const size_t CHPP = (size_t)CH * PP;

  if (ws_size >= 354 * MB) {
    // ---- fully batched path: 5 launches, 353 MB ----
    // Wf 1MB @0 | Qh/Ql/Kh/Kl 4x8MB @1..33 | Vbf 64MB @33 | S 256MB @97
    _Float16* Wf       = (_Float16*)w;
    unsigned short* Qh = (unsigned short*)(w + 1 * MB);
    unsigned short* Ql = (unsigned short*)(w + 9 * MB);
    unsigned short* Kh = (unsigned short*)(w + 17 * MB);
    unsigned short* Kl = (unsigned short*)(w + 25 * MB);
    unsigned short* Vbf = (unsigned short*)(w + 33 * MB);
    float* S           = (float*)(w + 97 * MB);

    prep_w<<<512, 256, 0, stream>>>(Wg, Wf);
    projXk<<<dim3(PP / 64, 1, 2 * BATCH), 256, 0, stream>>>(
        Xq, Xp, Wf, bias, Qh, Ql, Kh, Kl, Vbf, 0, 0);
    scr8<<<dim3(PP / 256, PP / 256, BATCH), 512, 0, stream>>>(Qh, Ql, Kh, Kl, S);
    softmax8<<<dim3(PP, BATCH), 256, 0, stream>>>(S);
    out8<<<dim3(PP / 256, CH / 256, BATCH), 512, 0, stream>>>(
        Vbf, (unsigned short*)S, out);
  } else {
    // ---- legacy 89MB per-batch path ----
    // Wf 1MB @0 | Qh/Ql/Kh/Kl 4x2MB @1..9 | Vbf 16MB @9 | S 64MB @25
    _Float16* Wf       = (_Float16*)w;
    unsigned short* Qh = (unsigned short*)(w + 1 * MB);
    unsigned short* Ql = (unsigned short*)(w + 3 * MB);
    unsigned short* Kh = (unsigned short*)(w + 5 * MB);
    unsigned short* Kl = (unsigned short*)(w + 7 * MB);
    unsigned short* Vbf = (unsigned short*)(w + 9 * MB);
    float* S           = (float*)(w + 25 * MB);

    prep_w<<<512, 256, 0, stream>>>(Wg, Wf);
    for (int b = 0; b < BATCH; ++b) {
      projXk<<<dim3(PP / 64, 1, 2), 256, 0, stream>>>(
          Xq, Xp, Wf, bias, Qh, Ql, Kh, Kl, Vbf, 2 * b, 1);
      scr8<<<dim3(PP / 256, PP / 256, 1), 512, 0, stream>>>(Qh, Ql, Kh, Kl, S);
      softmax8<<<dim3(PP, 1), 256, 0, stream>>>(S);
      out8<<<dim3(PP / 256, CH / 256, 1), 512, 0, stream>>>(
          Vbf, (unsigned short*)S, out + (size_t)b * CHPP);
    }
  }
}